// Round 1
// baseline (315.166 us; speedup 1.0000x reference)
//
#include <hip/hip_runtime.h>
#include <math.h>

namespace {

constexpr int H = 512;
constexpr int L = 4096;

// ws float layout
constexpr int WS_SU  = 0;     // 512: column sums of W_sh_upper
constexpr int WS_SL  = 512;   // 512: column sums of W_sh_lower
constexpr int WS_P   = 1024;  // 4*512: p_uu, p_ul, p_lu, p_ll
constexpr int WS_ACC = 3072;  // 1: loc_vec accumulator

__device__ inline float wave_reduce(float v) {
#pragma unroll
    for (int off = 32; off; off >>= 1) v += __shfl_xor(v, off, 64);
    return v;
}

// su[h] = sum_m W_sh_upper[m,h]; sl[h] = sum_m W_sh_lower[m,h]. Also zero acc.
__global__ void colsum_k(const float* __restrict__ Wsu,
                         const float* __restrict__ Wsl,
                         float* __restrict__ ws) {
    const int b = blockIdx.x;  // 8 blocks x 128 threads
    const int col = (b & 3) * 128 + threadIdx.x;
    const float* W = (b < 4) ? Wsu : Wsl;
    float acc = 0.f;
#pragma unroll 8
    for (int m = 0; m < H; ++m) acc += W[m * H + col];
    ws[((b < 4) ? WS_SU : WS_SL) + col] = acc;
    if (b == 0 && threadIdx.x == 0) ws[WS_ACC] = 0.f;
}

// p_v[j] = sum_h s[h] * W[h,j] for the 4 (s, W_th) combos
__global__ void pvec_k(const float* __restrict__ Wtu,
                       const float* __restrict__ Wtl,
                       float* __restrict__ ws) {
    const int v = blockIdx.x >> 2;             // 0:uu 1:ul 2:lu 3:ll
    const int j = (blockIdx.x & 3) * 128 + threadIdx.x;
    const float* s = ws + ((v < 2) ? WS_SU : WS_SL);
    const float* W = (v & 1) ? Wtl : Wtu;
    float acc = 0.f;
    for (int h = 0; h < H; ++h) acc += s[h] * W[h * H + j];
    ws[WS_P + v * H + j] = acc;
}

// per-row: rowsum_i = emb_i · (al*p_uu + be*p_ul + ga*p_lu + de*p_ll)
__global__ __launch_bounds__(512) void rowdot_k(
    const float* __restrict__ tu, const float* __restrict__ tl,
    const float* __restrict__ lu, const float* __restrict__ ll,
    const int* __restrict__ loc, const float* __restrict__ table,
    float* __restrict__ ws) {
    const int lane = threadIdx.x & 63;
    const int wid  = threadIdx.x >> 6;
    const int jA = lane * 4;        // cols [jA, jA+4)
    const int jB = 256 + lane * 4;  // cols [jB, jB+4)
    const float4* P = reinterpret_cast<const float4*>(ws + WS_P);
    const float4 puuA = P[(0 * H + jA) >> 2], puuB = P[(0 * H + jB) >> 2];
    const float4 pulA = P[(1 * H + jA) >> 2], pulB = P[(1 * H + jB) >> 2];
    const float4 pluA = P[(2 * H + jA) >> 2], pluB = P[(2 * H + jB) >> 2];
    const float4 pllA = P[(3 * H + jA) >> 2], pllB = P[(3 * H + jB) >> 2];

    float s_acc = 0.f;
    const int row0 = blockIdx.x * 32 + wid * 4;  // 128 blocks * 8 waves * 4 rows
#pragma unroll
    for (int r = 0; r < 4; ++r) {
        const int row = row0 + r;
        const float tuv = tu[row], tlv = tl[row];
        const float luv = lu[row], llv = ll[row];
        const float inv = 1.f / ((tuv + tlv) * (luv + llv));
        const float al = luv * tuv * inv;
        const float be = luv * tlv * inv;
        const float ga = llv * tuv * inv;
        const float de = llv * tlv * inv;
        const size_t base = (size_t)loc[row] * H;
        const float4 eA = *reinterpret_cast<const float4*>(table + base + jA);
        const float4 eB = *reinterpret_cast<const float4*>(table + base + jB);
        s_acc += eA.x * (al * puuA.x + be * pulA.x + ga * pluA.x + de * pllA.x);
        s_acc += eA.y * (al * puuA.y + be * pulA.y + ga * pluA.y + de * pllA.y);
        s_acc += eA.z * (al * puuA.z + be * pulA.z + ga * pluA.z + de * pllA.z);
        s_acc += eA.w * (al * puuA.w + be * pulA.w + ga * pluA.w + de * pllA.w);
        s_acc += eB.x * (al * puuB.x + be * pulB.x + ga * pluB.x + de * pllB.x);
        s_acc += eB.y * (al * puuB.y + be * pulB.y + ga * pluB.y + de * pllB.y);
        s_acc += eB.z * (al * puuB.z + be * pulB.z + ga * pluB.z + de * pllB.z);
        s_acc += eB.w * (al * puuB.w + be * pulB.w + ga * pluB.w + de * pllB.w);
    }
    s_acc = wave_reduce(s_acc);
    __shared__ float wpart[8];
    if (lane == 0) wpart[wid] = s_acc;
    __syncthreads();
    if (threadIdx.x == 0) {
        float t = 0.f;
#pragma unroll
        for (int w = 0; w < 8; ++w) t += wpart[w];
        atomicAdd(ws + WS_ACC, t);
    }
}

// out[h] = sigmoid(loc_vec + (W_ih @ hx)[h]); one wave per output row
__global__ __launch_bounds__(256) void out_k(
    const float* __restrict__ Wih, const float* __restrict__ hx,
    const float* __restrict__ ws, float* __restrict__ out) {
    const int lane = threadIdx.x & 63;
    const int wid  = threadIdx.x >> 6;
    const int row  = blockIdx.x * 4 + wid;  // 128 blocks * 4 waves = 512 rows
    const int jA = lane * 4, jB = 256 + lane * 4;
    const float4 wA = *reinterpret_cast<const float4*>(Wih + row * H + jA);
    const float4 wB = *reinterpret_cast<const float4*>(Wih + row * H + jB);
    const float4 xA = *reinterpret_cast<const float4*>(hx + jA);
    const float4 xB = *reinterpret_cast<const float4*>(hx + jB);
    float acc = wA.x * xA.x + wA.y * xA.y + wA.z * xA.z + wA.w * xA.w
              + wB.x * xB.x + wB.y * xB.y + wB.z * xB.z + wB.w * xB.w;
    acc = wave_reduce(acc);
    if (lane == 0) {
        const float x = acc + ws[WS_ACC];
        out[row] = 1.f / (1.f + expf(-x));
    }
}

}  // namespace

extern "C" void kernel_launch(void* const* d_in, const int* in_sizes, int n_in,
                              void* d_out, int out_size, void* d_ws, size_t ws_size,
                              hipStream_t stream) {
    const float* tu    = (const float*)d_in[0];
    const float* tl    = (const float*)d_in[1];
    const float* lu    = (const float*)d_in[2];
    const float* ll    = (const float*)d_in[3];
    const int*   loc   = (const int*)d_in[4];
    const float* hx    = (const float*)d_in[5];
    const float* Wih   = (const float*)d_in[6];
    const float* Wtu   = (const float*)d_in[7];
    const float* Wtl   = (const float*)d_in[8];
    const float* Wsu   = (const float*)d_in[9];
    const float* Wsl   = (const float*)d_in[10];
    const float* table = (const float*)d_in[11];
    float* ws  = (float*)d_ws;
    float* out = (float*)d_out;

    colsum_k<<<8, 128, 0, stream>>>(Wsu, Wsl, ws);
    pvec_k<<<16, 128, 0, stream>>>(Wtu, Wtl, ws);
    rowdot_k<<<128, 512, 0, stream>>>(tu, tl, lu, ll, loc, table, ws);
    out_k<<<128, 256, 0, stream>>>(Wih, hx, ws, out);
}

// Round 4
// 284.960 us; speedup vs baseline: 1.1060x; 1.1060x over previous
//
#include <hip/hip_runtime.h>
#include <math.h>

namespace {

constexpr int H = 512;
constexpr int L = 4096;

// ws float offsets
constexpr int WS_SU  = 0;      // 512: colsum of W_sh_upper
constexpr int WS_SL  = 512;    // 512: colsum of W_sh_lower
constexpr int WS_G   = 1024;   // 4*512: g_alpha, g_beta, g_gamma, g_delta
constexpr int WS_IHV = 3072;   // 512: W_ih @ hx
constexpr int WS_ACC = 3584;   // 1: loc_vec scalar
constexpr int WS_TOT = 3585;

constexpr int GB = 256;  // gather blocks, 16 rows each
constexpr int CB = 128;  // colsum blocks, 8 rows each (64 per matrix)
constexpr int WB = 8;    // W_ih@hx blocks, 64 rows each

__device__ inline float wave_reduce(float v) {
#pragma unroll
    for (int off = 32; off; off >>= 1) v += __shfl_xor(v, off, 64);
    return v;
}

// Stage A: three independent sub-tasks, selected by blockIdx.
//  [0,GB):       g_xy[j] += coef_xy(i) * table[loc[i]][j]  (atomics)
//  [GB,GB+CB):   su/sl[j] += colsum partials               (atomics)
//  [GB+CB,+WB):  ihv[row] = W_ih[row,:] . hx               (plain store)
__global__ __launch_bounds__(512) void stageA_k(
    const float* __restrict__ tu, const float* __restrict__ tl,
    const float* __restrict__ lu, const float* __restrict__ ll,
    const int* __restrict__ loc, const float* __restrict__ table,
    const float* __restrict__ Wsu, const float* __restrict__ Wsl,
    const float* __restrict__ Wih, const float* __restrict__ hx,
    float* __restrict__ ws) {
    const int b = blockIdx.x;
    const int t = threadIdx.x;
    if (b < GB) {
        float aa = 0.f, ab = 0.f, ag = 0.f, ad = 0.f;
        const int row0 = b * (L / GB);
#pragma unroll
        for (int r = 0; r < L / GB; ++r) {
            const int row = row0 + r;
            const float tuv = tu[row], tlv = tl[row];
            const float luv = lu[row], llv = ll[row];
            const float ti = 1.f / (tuv + tlv), li = 1.f / (luv + llv);
            const float Tu = tuv * ti, Tl = tlv * ti;
            const float Lu = luv * li, Ll = llv * li;
            const float e = table[(size_t)loc[row] * H + t];
            aa += Lu * Tu * e;
            ab += Lu * Tl * e;
            ag += Ll * Tu * e;
            ad += Ll * Tl * e;
        }
        atomicAdd(ws + WS_G + 0 * H + t, aa);
        atomicAdd(ws + WS_G + 1 * H + t, ab);
        atomicAdd(ws + WS_G + 2 * H + t, ag);
        atomicAdd(ws + WS_G + 3 * H + t, ad);
    } else if (b < GB + CB) {
        const int cb = b - GB;
        const int mat = cb >> 6;            // 0: Wsu, 1: Wsl
        const int m0 = (cb & 63) * (H / 64);
        const float* W = mat ? Wsl : Wsu;
        float acc = 0.f;
#pragma unroll
        for (int r = 0; r < H / 64; ++r) acc += W[(size_t)(m0 + r) * H + t];
        atomicAdd(ws + (mat ? WS_SL : WS_SU) + t, acc);
    } else {
        const int wb = b - GB - CB;
        const int lane = t & 63, wid = t >> 6;
        const int j = lane * 8;
        const float4 xA = *reinterpret_cast<const float4*>(hx + j);
        const float4 xB = *reinterpret_cast<const float4*>(hx + j + 4);
#pragma unroll
        for (int r = 0; r < 8; ++r) {
            const int row = wb * 64 + wid * 8 + r;
            const float4 wA = *reinterpret_cast<const float4*>(Wih + (size_t)row * H + j);
            const float4 wB = *reinterpret_cast<const float4*>(Wih + (size_t)row * H + j + 4);
            float a = wA.x * xA.x + wA.y * xA.y + wA.z * xA.z + wA.w * xA.w
                    + wB.x * xB.x + wB.y * xB.y + wB.z * xB.z + wB.w * xB.w;
            a = wave_reduce(a);
            if (lane == 0) ws[WS_IHV + row] = a;
        }
    }
}

// Stage B: loc_vec = sum_h Wtu[h,:].(su[h] g_a + sl[h] g_g)
//                  + sum_h Wtl[h,:].(su[h] g_b + sl[h] g_d)
// One wave per (matrix, h); 1024 waves; each matrix read once.
__global__ __launch_bounds__(512) void stageB_k(
    const float* __restrict__ Wtu, const float* __restrict__ Wtl,
    float* __restrict__ ws) {
    const int t = threadIdx.x;
    const int lane = t & 63, wid = t >> 6;
    const int gw = blockIdx.x * 8 + wid;  // [0, 1024)
    const int mat = gw >> 9;              // 0: Wtu, 1: Wtl
    const int h = gw & (H - 1);
    const float* W = mat ? Wtl : Wtu;
    const float* g1 = ws + WS_G + (mat ? 1 : 0) * H;  // pairs with su
    const float* g2 = ws + WS_G + (mat ? 3 : 2) * H;  // pairs with sl
    const float suh = ws[WS_SU + h], slh = ws[WS_SL + h];
    const int j = lane * 8;
    const float4 wA = *reinterpret_cast<const float4*>(W + (size_t)h * H + j);
    const float4 wB = *reinterpret_cast<const float4*>(W + (size_t)h * H + j + 4);
    const float4 aA = *reinterpret_cast<const float4*>(g1 + j);
    const float4 aB = *reinterpret_cast<const float4*>(g1 + j + 4);
    const float4 bA = *reinterpret_cast<const float4*>(g2 + j);
    const float4 bB = *reinterpret_cast<const float4*>(g2 + j + 4);
    float acc = wA.x * (suh * aA.x + slh * bA.x)
              + wA.y * (suh * aA.y + slh * bA.y)
              + wA.z * (suh * aA.z + slh * bA.z)
              + wA.w * (suh * aA.w + slh * bA.w)
              + wB.x * (suh * aB.x + slh * bB.x)
              + wB.y * (suh * aB.y + slh * bB.y)
              + wB.z * (suh * aB.z + slh * bB.z)
              + wB.w * (suh * aB.w + slh * bB.w);
    acc = wave_reduce(acc);
    if (lane == 0) atomicAdd(ws + WS_ACC, acc);
}

// Stage C: out[h] = sigmoid(loc_vec + ihv[h])
__global__ __launch_bounds__(512) void stageC_k(
    const float* __restrict__ ws, float* __restrict__ out) {
    const int t = threadIdx.x;
    const float x = ws[WS_ACC] + ws[WS_IHV + t];
    out[t] = 1.f / (1.f + expf(-x));
}

}  // namespace

extern "C" void kernel_launch(void* const* d_in, const int* in_sizes, int n_in,
                              void* d_out, int out_size, void* d_ws, size_t ws_size,
                              hipStream_t stream) {
    const float* tu    = (const float*)d_in[0];
    const float* tl    = (const float*)d_in[1];
    const float* lu    = (const float*)d_in[2];
    const float* ll    = (const float*)d_in[3];
    const int*   loc   = (const int*)d_in[4];
    const float* hx    = (const float*)d_in[5];
    const float* Wih   = (const float*)d_in[6];
    const float* Wtu   = (const float*)d_in[7];
    const float* Wtl   = (const float*)d_in[8];
    const float* Wsu   = (const float*)d_in[9];
    const float* Wsl   = (const float*)d_in[10];
    const float* table = (const float*)d_in[11];
    float* ws  = (float*)d_ws;
    float* out = (float*)d_out;

    hipMemsetAsync(ws, 0, WS_TOT * sizeof(float), stream);
    stageA_k<<<GB + CB + WB, 512, 0, stream>>>(tu, tl, lu, ll, loc, table,
                                               Wsu, Wsl, Wih, hx, ws);
    stageB_k<<<128, 512, 0, stream>>>(Wtu, Wtl, ws);
    stageC_k<<<1, 512, 0, stream>>>(ws, out);
}

// Round 6
// 274.554 us; speedup vs baseline: 1.1479x; 1.0379x over previous
//
#include <hip/hip_runtime.h>
#include <math.h>

namespace {

constexpr int H = 512;
constexpr int L = 4096;
constexpr int REPG = 8;  // gather accumulator replicas (cuts atomic contention)
constexpr int REPS = 4;  // colsum accumulator replicas

// ws float offsets
constexpr int WS_SU  = 0;                      // REPS*H
constexpr int WS_SL  = WS_SU + REPS * H;       // REPS*H
constexpr int WS_G   = WS_SL + REPS * H;       // REPG*4*H
constexpr int WS_IHV = WS_G + REPG * 4 * H;    // H
constexpr int WS_ACC = WS_IHV + H;             // 1
constexpr int WS_CNT = WS_ACC + 1;             // 1 (int)
constexpr int WS_TOT = WS_CNT + 1;

constexpr int GB = 128;  // gather blocks, 32 rows each
constexpr int CB = 128;  // colsum blocks, 8 rows each (64 per matrix)
constexpr int WB = 8;    // W_ih@hx blocks, 64 rows each
constexpr int BGRID = 128;  // stageB grid

__device__ inline float wave_reduce(float v) {
#pragma unroll
    for (int off = 32; off; off >>= 1) v += __shfl_xor(v, off, 64);
    return v;
}

// Stage A: three independent sub-tasks, selected by blockIdx.
//  [0,GB):       g_rep[b%REPG][v][j] += coef_v(i) * table[loc[i]][j]
//  [GB,GB+CB):   su/sl replica partial colsums (atomics)
//  [GB+CB,+WB):  ihv[row] = W_ih[row,:] . hx  (plain store)
__global__ __launch_bounds__(512) void stageA_k(
    const float* __restrict__ tu, const float* __restrict__ tl,
    const float* __restrict__ lu, const float* __restrict__ ll,
    const int* __restrict__ loc, const float* __restrict__ table,
    const float* __restrict__ Wsu, const float* __restrict__ Wsl,
    const float* __restrict__ Wih, const float* __restrict__ hx,
    float* __restrict__ ws) {
    const int b = blockIdx.x;
    const int t = threadIdx.x;
    if (b < GB) {
        const int rep = b & (REPG - 1);
        float aa = 0.f, ab = 0.f, ag = 0.f, ad = 0.f;
        const int row0 = b * (L / GB);
#pragma unroll 16
        for (int r = 0; r < L / GB; ++r) {
            const int row = row0 + r;
            const float tuv = tu[row], tlv = tl[row];
            const float luv = lu[row], llv = ll[row];
            const float ti = 1.f / (tuv + tlv), li = 1.f / (luv + llv);
            const float Tu = tuv * ti, Tl = tlv * ti;
            const float Lu = luv * li, Ll = llv * li;
            const float e = table[(size_t)loc[row] * H + t];
            aa += Lu * Tu * e;
            ab += Lu * Tl * e;
            ag += Ll * Tu * e;
            ad += Ll * Tl * e;
        }
        float* g = ws + WS_G + rep * (4 * H);
        atomicAdd(g + 0 * H + t, aa);
        atomicAdd(g + 1 * H + t, ab);
        atomicAdd(g + 2 * H + t, ag);
        atomicAdd(g + 3 * H + t, ad);
    } else if (b < GB + CB) {
        const int cb = b - GB;
        const int mat = cb >> 6;            // 0: Wsu, 1: Wsl
        const int q = cb & 63;
        const int m0 = q * (H / 64);
        const int rep = q & (REPS - 1);
        const float* W = mat ? Wsl : Wsu;
        float acc = 0.f;
#pragma unroll
        for (int r = 0; r < H / 64; ++r) acc += W[(size_t)(m0 + r) * H + t];
        atomicAdd(ws + (mat ? WS_SL : WS_SU) + rep * H + t, acc);
    } else {
        const int wb = b - GB - CB;
        const int lane = t & 63, wid = t >> 6;
        const int j = lane * 8;
        const float4 xA = *reinterpret_cast<const float4*>(hx + j);
        const float4 xB = *reinterpret_cast<const float4*>(hx + j + 4);
#pragma unroll
        for (int r = 0; r < 8; ++r) {
            const int row = wb * 64 + wid * 8 + r;
            const float4 wA = *reinterpret_cast<const float4*>(Wih + (size_t)row * H + j);
            const float4 wB = *reinterpret_cast<const float4*>(Wih + (size_t)row * H + j + 4);
            float a = wA.x * xA.x + wA.y * xA.y + wA.z * xA.z + wA.w * xA.w
                    + wB.x * xB.x + wB.y * xB.y + wB.z * xB.z + wB.w * xB.w;
            a = wave_reduce(a);
            if (lane == 0) ws[WS_IHV + row] = a;
        }
    }
}

// Stage B: loc_vec = sum over (mat, h) of W[h,:].(s1[h] gA + s2[h] gB),
// then the LAST block computes out[h] = sigmoid(loc_vec + ihv[h]).
__global__ __launch_bounds__(512) void stageB_k(
    const float* __restrict__ Wtu, const float* __restrict__ Wtl,
    float* __restrict__ ws, float* __restrict__ out) {
    const int t = threadIdx.x;
    const int lane = t & 63, wid = t >> 6;
    const int gw = blockIdx.x * 8 + wid;  // [0, 1024)
    const int mat = gw >> 9;              // 0: Wtu, 1: Wtl
    const int h = gw & (H - 1);
    const float* W = mat ? Wtl : Wtu;
    const int v1 = mat ? 1 : 0;  // pairs with su
    const int v2 = mat ? 3 : 2;  // pairs with sl

    float suh = 0.f, slh = 0.f;
#pragma unroll
    for (int rp = 0; rp < REPS; ++rp) {
        suh += ws[WS_SU + rp * H + h];
        slh += ws[WS_SL + rp * H + h];
    }

    const int j = lane * 8;
    float a1[8] = {0, 0, 0, 0, 0, 0, 0, 0};
    float a2[8] = {0, 0, 0, 0, 0, 0, 0, 0};
#pragma unroll
    for (int rp = 0; rp < REPG; ++rp) {
        const float* g1 = ws + WS_G + (rp * 4 + v1) * H + j;
        const float* g2 = ws + WS_G + (rp * 4 + v2) * H + j;
        const float4 x0 = *reinterpret_cast<const float4*>(g1);
        const float4 x1 = *reinterpret_cast<const float4*>(g1 + 4);
        const float4 y0 = *reinterpret_cast<const float4*>(g2);
        const float4 y1 = *reinterpret_cast<const float4*>(g2 + 4);
        a1[0] += x0.x; a1[1] += x0.y; a1[2] += x0.z; a1[3] += x0.w;
        a1[4] += x1.x; a1[5] += x1.y; a1[6] += x1.z; a1[7] += x1.w;
        a2[0] += y0.x; a2[1] += y0.y; a2[2] += y0.z; a2[3] += y0.w;
        a2[4] += y1.x; a2[5] += y1.y; a2[6] += y1.z; a2[7] += y1.w;
    }

    const float4 wA = *reinterpret_cast<const float4*>(W + (size_t)h * H + j);
    const float4 wB = *reinterpret_cast<const float4*>(W + (size_t)h * H + j + 4);
    float acc = wA.x * (suh * a1[0] + slh * a2[0])
              + wA.y * (suh * a1[1] + slh * a2[1])
              + wA.z * (suh * a1[2] + slh * a2[2])
              + wA.w * (suh * a1[3] + slh * a2[3])
              + wB.x * (suh * a1[4] + slh * a2[4])
              + wB.y * (suh * a1[5] + slh * a2[5])
              + wB.z * (suh * a1[6] + slh * a2[6])
              + wB.w * (suh * a1[7] + slh * a2[7]);
    acc = wave_reduce(acc);

    __shared__ float wp[8];
    __shared__ float accs;
    __shared__ int lastf;
    if (lane == 0) wp[wid] = acc;
    __syncthreads();
    if (t == 0) {
        float s = 0.f;
#pragma unroll
        for (int w = 0; w < 8; ++w) s += wp[w];
        atomicAdd(ws + WS_ACC, s);
        __threadfence();
        const int old = atomicAdd(reinterpret_cast<int*>(ws) + WS_CNT, 1);
        lastf = (old == (int)gridDim.x - 1) ? 1 : 0;
    }
    __syncthreads();
    if (lastf) {
        if (t == 0) accs = atomicAdd(ws + WS_ACC, 0.0f);  // read at coherence point
        __syncthreads();
        const float x = accs + ws[WS_IHV + t];
        out[t] = 1.f / (1.f + expf(-x));
    }
}

}  // namespace

extern "C" void kernel_launch(void* const* d_in, const int* in_sizes, int n_in,
                              void* d_out, int out_size, void* d_ws, size_t ws_size,
                              hipStream_t stream) {
    const float* tu    = (const float*)d_in[0];
    const float* tl    = (const float*)d_in[1];
    const float* lu    = (const float*)d_in[2];
    const float* ll    = (const float*)d_in[3];
    const int*   loc   = (const int*)d_in[4];
    const float* hx    = (const float*)d_in[5];
    const float* Wih   = (const float*)d_in[6];
    const float* Wtu   = (const float*)d_in[7];
    const float* Wtl   = (const float*)d_in[8];
    const float* Wsu   = (const float*)d_in[9];
    const float* Wsl   = (const float*)d_in[10];
    const float* table = (const float*)d_in[11];
    float* ws  = (float*)d_ws;
    float* out = (float*)d_out;

    hipMemsetAsync(ws, 0, WS_TOT * sizeof(float), stream);
    stageA_k<<<GB + CB + WB, 512, 0, stream>>>(tu, tl, lu, ll, loc, table,
                                               Wsu, Wsl, Wih, hx, ws);
    stageB_k<<<BGRID, 512, 0, stream>>>(Wtu, Wtl, ws, out);
}